// Round 7
// baseline (346.352 us; speedup 1.0000x reference)
//
#include <hip/hip_runtime.h>
#include <hip/hip_bf16.h>
#include <math.h>

// Problem constants (fixed by setup_inputs)
#define S_   64
#define H_   32
#define D_   128
#define KVH_ 8
#define G_   4
#define BS_  16
#define MB_  128
#define LMAX_ 2048
#define PART_ 256
#define MAXP_ (LMAX_ / PART_)   // 8

#define SCALE_ 0.08838834764831845f  // 1/sqrt(128)
#define MINIT_ -1.0e30f              // finite "neg-inf": corr=exp(m-mn) never NaN

// One WG (256 thr = 8 groups of 32 lanes) per (seq, kv_head, 256-token
// partition). Each group owns 2 consecutive 16-token pages = 8 batches of 4
// tokens, processed with a register double-buffer: batch i+1's 8 float4
// loads are issued (unconditionally, clamped index at the tail) before
// batch i's compute, separated by sched_barrier(0) so the scheduler keeps
// the pipeline exactly 2 deep (WAR on the 2-slot buffer bounds it above).
// No branches around loads -> compiler emits counted vmcnt, prefetch stays
// in flight under compute. Lane owns a float4 slice of D.
__global__ __launch_bounds__(256)
void pa_partial(const float* __restrict__ q,
                const float* __restrict__ kc,
                const float* __restrict__ vc,
                const int* __restrict__ bt,
                const int* __restrict__ cl,
                float* __restrict__ ws)
{
    const int s    = blockIdx.z;
    const int kvh  = blockIdx.y;
    const int part = blockIdx.x;

    const int len = cl[s];
    const int t0  = part * PART_;
    if (t0 >= len) return;

    const int tid  = threadIdx.x;
    const int gid  = tid >> 5;   // 0..7
    const int l32  = tid & 31;   // 0..31

    const int t_base = t0 + gid * 32;      // group's first token
    const int nv     = len - t_base;       // valid tokens for this group

    float  m[G_], l[G_];
    float4 acc[G_];
#pragma unroll
    for (int g = 0; g < G_; ++g) {
        m[g] = MINIT_; l[g] = 0.f;
        acc[g] = make_float4(0.f, 0.f, 0.f, 0.f);
    }

    if (nv > 0) {
        // Q fragments: 4 heads, each lane holds float4 at d = l32*4
        float4 qv[G_];
#pragma unroll
        for (int g = 0; g < G_; ++g)
            qv[g] = *(const float4*)(q + ((size_t)(s * H_ + kvh * G_ + g)) * D_ + l32 * 4);

        const int* btr = bt + s * MB_;
        const size_t kvh_off = (size_t)kvh * (BS_ * D_);

        // Two pages cover the group's 32 tokens; page0+1 <= 127 always.
        const int page0 = (t0 >> 4) + gid * 2;
        const int bid0  = btr[page0];
        const int bid1  = btr[page0 + 1];
        const float* kp0 = kc + (size_t)bid0 * (KVH_ * BS_ * D_) + kvh_off + l32 * 4;
        const float* vp0 = vc + (size_t)bid0 * (KVH_ * BS_ * D_) + kvh_off + l32 * 4;
        const float* kp1 = kc + (size_t)bid1 * (KVH_ * BS_ * D_) + kvh_off + l32 * 4;
        const float* vp1 = vc + (size_t)bid1 * (KVH_ * BS_ * D_) + kvh_off + l32 * 4;

        float4 kb[2][4], vb[2][4];
        // Prologue: batch 0 (page 0, rows 0..3).
#pragma unroll
        for (int r = 0; r < 4; ++r) kb[0][r] = *(const float4*)(kp0 + (size_t)r * D_);
#pragma unroll
        for (int r = 0; r < 4; ++r) vb[0][r] = *(const float4*)(vp0 + (size_t)r * D_);

#pragma unroll
        for (int b = 0; b < 8; ++b) {
            const int cur = b & 1, nxt = cur ^ 1;

            // Unconditional prefetch of batch b+1 (clamped at tail: reloads
            // batch 7's rows, which hit L1 — keeps code branch-free).
            const int bp = (b < 7) ? b + 1 : 7;
            const float* kpp = (bp < 4 ? kp0 : kp1) + (size_t)((bp & 3) * 4) * D_;
            const float* vpp = (bp < 4 ? vp0 : vp1) + (size_t)((bp & 3) * 4) * D_;
#pragma unroll
            for (int r = 0; r < 4; ++r) kb[nxt][r] = *(const float4*)(kpp + (size_t)r * D_);
#pragma unroll
            for (int r = 0; r < 4; ++r) vb[nxt][r] = *(const float4*)(vpp + (size_t)r * D_);

            // Fence: loads above stay above, compute below stays below.
            __builtin_amdgcn_sched_barrier(0);

            // Partial dots: 16 independent values.
            float sc[4][G_];
#pragma unroll
            for (int i = 0; i < 4; ++i)
#pragma unroll
                for (int g = 0; g < G_; ++g)
                    sc[i][g] = qv[g].x * kb[cur][i].x + qv[g].y * kb[cur][i].y +
                               qv[g].z * kb[cur][i].z + qv[g].w * kb[cur][i].w;

            // Butterfly reduce across 32 lanes; 16 chains pipeline.
#pragma unroll
            for (int off = 16; off; off >>= 1)
#pragma unroll
                for (int i = 0; i < 4; ++i)
#pragma unroll
                    for (int g = 0; g < G_; ++g)
                        sc[i][g] += __shfl_xor(sc[i][g], off, 32);

            // Scale + mask tokens beyond nv.
#pragma unroll
            for (int i = 0; i < 4; ++i) {
                const bool valid = (b * 4 + i) < nv;
#pragma unroll
                for (int g = 0; g < G_; ++g)
                    sc[i][g] = valid ? sc[i][g] * SCALE_ : -INFINITY;
            }

            // Online-softmax update (m finite always; masked p -> 0).
#pragma unroll
            for (int g = 0; g < G_; ++g) {
                const float smax = fmaxf(fmaxf(sc[0][g], sc[1][g]),
                                         fmaxf(sc[2][g], sc[3][g]));
                const float mn   = fmaxf(m[g], smax);
                const float corr = __expf(m[g] - mn);
                const float p0 = __expf(sc[0][g] - mn);
                const float p1 = __expf(sc[1][g] - mn);
                const float p2 = __expf(sc[2][g] - mn);
                const float p3 = __expf(sc[3][g] - mn);
                l[g] = l[g] * corr + ((p0 + p1) + (p2 + p3));
                acc[g].x = acc[g].x * corr + p0 * vb[cur][0].x + p1 * vb[cur][1].x + p2 * vb[cur][2].x + p3 * vb[cur][3].x;
                acc[g].y = acc[g].y * corr + p0 * vb[cur][0].y + p1 * vb[cur][1].y + p2 * vb[cur][2].y + p3 * vb[cur][3].y;
                acc[g].z = acc[g].z * corr + p0 * vb[cur][0].z + p1 * vb[cur][1].z + p2 * vb[cur][2].z + p3 * vb[cur][3].z;
                acc[g].w = acc[g].w * corr + p0 * vb[cur][0].w + p1 * vb[cur][1].w + p2 * vb[cur][2].w + p3 * vb[cur][3].w;
                m[g] = mn;
            }
        }
    }

    // Combine the 8 groups inside the WG via LDS.
    __shared__ float lm[8][G_];
    __shared__ float ll[8][G_];
    __shared__ float lacc[8][G_][D_];   // 16 KB

#pragma unroll
    for (int g = 0; g < G_; ++g) {
        if (l32 == 0) { lm[gid][g] = m[g]; ll[gid][g] = l[g]; }
        *(float4*)&lacc[gid][g][l32 * 4] = acc[g];
    }
    __syncthreads();

    // 512 (g,d) elements over 256 threads: 2 each. Group 0 is always
    // non-empty (t0 < len); empty groups carry (MINIT_, 0, 0) -> weight 0.
    float* pbase = ws + (((size_t)(s * KVH_ + kvh) * MAXP_ + part) * G_) * 130;
#pragma unroll
    for (int i = 0; i < 2; ++i) {
        const int idx = tid + 256 * i;
        const int g = idx >> 7;
        const int d = idx & 127;
        float M = lm[0][g];
#pragma unroll
        for (int r = 1; r < 8; ++r) M = fmaxf(M, lm[r][g]);
        float L = 0.f, val = 0.f;
#pragma unroll
        for (int r = 0; r < 8; ++r) {
            const float w = __expf(lm[r][g] - M);
            L   += w * ll[r][g];
            val += w * lacc[r][g][d];
        }
        float* pb = pbase + (size_t)g * 130;
        if (d == 0) { pb[0] = M; pb[1] = L; }
        pb[2 + d] = val;
    }
}

// Combine kernel: one WG (128 threads) per (seq, head); reduce over partitions.
__global__ __launch_bounds__(128)
void pa_combine(const float* __restrict__ ws,
                const int* __restrict__ cl,
                float* __restrict__ out)
{
    const int h = blockIdx.x;   // 0..31
    const int s = blockIdx.y;   // 0..63
    const int kvh = h >> 2;
    const int g   = h & 3;
    const int d   = threadIdx.x;

    const int len = cl[s];
    const int np  = (len + PART_ - 1) / PART_;

    const float* base = ws + ((size_t)(s * KVH_ + kvh) * MAXP_) * (G_ * 130) + (size_t)g * 130;

    float M = MINIT_;
    for (int p = 0; p < np; ++p) M = fmaxf(M, base[(size_t)p * (G_ * 130)]);

    float L = 0.f, val = 0.f;
    for (int p = 0; p < np; ++p) {
        const float* pb = base + (size_t)p * (G_ * 130);
        const float w = __expf(pb[0] - M);
        L   += w * pb[1];
        val += w * pb[2 + d];
    }
    out[((size_t)s * H_ + h) * D_ + d] = val / L;
}

extern "C" void kernel_launch(void* const* d_in, const int* in_sizes, int n_in,
                              void* d_out, int out_size, void* d_ws, size_t ws_size,
                              hipStream_t stream)
{
    const float* q  = (const float*)d_in[0];
    const float* kc = (const float*)d_in[1];
    const float* vc = (const float*)d_in[2];
    const int*   bt = (const int*)d_in[3];
    const int*   cl = (const int*)d_in[4];
    float* out = (float*)d_out;
    float* ws  = (float*)d_ws;

    // ws layout: [S_][KVH_][MAXP_][G_][130] floats = 8.5 MB.
    dim3 grid1(MAXP_, KVH_, S_);
    pa_partial<<<grid1, 256, 0, stream>>>(q, kc, vc, bt, cl, ws);

    dim3 grid2(H_, S_);
    pa_combine<<<grid2, 128, 0, stream>>>(ws, cl, out);
}

// Round 8
// 161.551 us; speedup vs baseline: 2.1439x; 2.1439x over previous
//
#include <hip/hip_runtime.h>
#include <hip/hip_bf16.h>
#include <math.h>

// Problem constants (fixed by setup_inputs)
#define S_   64
#define H_   32
#define D_   128
#define KVH_ 8
#define G_   4
#define BS_  16
#define MB_  128
#define LMAX_ 2048
#define PART_ 128
#define MAXP_ (LMAX_ / PART_)          // 16
#define ITEMS_ (S_ * KVH_ * MAXP_)     // 8192 work items
#define NWG_  2048                     // 8 WGs/CU * 256 CUs

#define SCALE_ 0.08838834764831845f  // 1/sqrt(128)
#define MINIT_ -1.0e30f              // finite "neg-inf": corr=exp(m-mn) never NaN

// Persistent-WG flash-decode partial kernel.
// 2048 WGs of 256 threads stay resident (LDS 16.9KB*8=135KB/CU, VGPR ~64-76)
// and steal (seq, kv_head, 128-token partition) items from a global atomic
// counter: no early-exit WG churn, no load imbalance from random context
// lens — CU wave slots stay full until work runs out.
// Per item: 8 groups of 32 lanes; group g owns one 16-token page, processed
// as 4 batches of 4 tokens (burst 8 float4 loads -> compute). Lane owns a
// float4 slice of D. Item's 4 GQA heads computed together per group.
__global__ __launch_bounds__(256)
void pa_partial(const float* __restrict__ q,
                const float* __restrict__ kc,
                const float* __restrict__ vc,
                const int* __restrict__ bt,
                const int* __restrict__ cl,
                float* __restrict__ ws,
                int* __restrict__ counter)
{
    const int tid  = threadIdx.x;
    const int gid  = tid >> 5;   // 0..7
    const int l32  = tid & 31;   // 0..31

    __shared__ int   s_item;
    __shared__ float lm[8][G_];
    __shared__ float ll[8][G_];
    __shared__ float lacc[8][G_][D_];   // 16 KB

    for (;;) {
        if (tid == 0) s_item = atomicAdd(counter, 1);
        __syncthreads();
        const int item = s_item;
        __syncthreads();   // s_item consumed; also fences lacc reuse
        if (item >= ITEMS_) return;

        const int part = item & (MAXP_ - 1);
        const int kvh  = (item >> 4) & (KVH_ - 1);
        const int s    = item >> 7;

        const int len = cl[s];
        const int t0  = part * PART_;
        if (t0 >= len) continue;   // uniform across WG

        const int t_base = t0 + gid * BS_;   // this group's page start
        const int nv     = len - t_base;     // valid tokens (may be <=0)

        float  m[G_], l[G_];
        float4 acc[G_];
#pragma unroll
        for (int g = 0; g < G_; ++g) {
            m[g] = MINIT_; l[g] = 0.f;
            acc[g] = make_float4(0.f, 0.f, 0.f, 0.f);
        }

        if (nv > 0) {
            float4 qv[G_];
#pragma unroll
            for (int g = 0; g < G_; ++g)
                qv[g] = *(const float4*)(q + ((size_t)(s * H_ + kvh * G_ + g)) * D_ + l32 * 4);

            const int bid = bt[s * MB_ + (t_base >> 4)];
            const float* kp = kc + (size_t)bid * (KVH_ * BS_ * D_)
                                 + (size_t)kvh * (BS_ * D_) + l32 * 4;
            const float* vp = vc + (size_t)bid * (KVH_ * BS_ * D_)
                                 + (size_t)kvh * (BS_ * D_) + l32 * 4;

#pragma unroll
            for (int b = 0; b < 4; ++b) {
                // Burst-load 4 K rows + 4 V rows (all rows of a valid page
                // exist; only scores are masked).
                float4 k4[4], v4[4];
#pragma unroll
                for (int i = 0; i < 4; ++i) {
                    k4[i] = *(const float4*)(kp + (size_t)(b * 4 + i) * D_);
                    v4[i] = *(const float4*)(vp + (size_t)(b * 4 + i) * D_);
                }

                float sc[4][G_];
#pragma unroll
                for (int i = 0; i < 4; ++i)
#pragma unroll
                    for (int g = 0; g < G_; ++g)
                        sc[i][g] = qv[g].x * k4[i].x + qv[g].y * k4[i].y +
                                   qv[g].z * k4[i].z + qv[g].w * k4[i].w;

#pragma unroll
                for (int off = 16; off; off >>= 1)
#pragma unroll
                    for (int i = 0; i < 4; ++i)
#pragma unroll
                        for (int g = 0; g < G_; ++g)
                            sc[i][g] += __shfl_xor(sc[i][g], off, 32);

#pragma unroll
                for (int i = 0; i < 4; ++i) {
                    const bool valid = (b * 4 + i) < nv;
#pragma unroll
                    for (int g = 0; g < G_; ++g)
                        sc[i][g] = valid ? sc[i][g] * SCALE_ : -INFINITY;
                }

#pragma unroll
                for (int g = 0; g < G_; ++g) {
                    const float smax = fmaxf(fmaxf(sc[0][g], sc[1][g]),
                                             fmaxf(sc[2][g], sc[3][g]));
                    const float mn   = fmaxf(m[g], smax);
                    const float corr = __expf(m[g] - mn);
                    const float p0 = __expf(sc[0][g] - mn);
                    const float p1 = __expf(sc[1][g] - mn);
                    const float p2 = __expf(sc[2][g] - mn);
                    const float p3 = __expf(sc[3][g] - mn);
                    l[g] = l[g] * corr + ((p0 + p1) + (p2 + p3));
                    acc[g].x = acc[g].x * corr + p0 * v4[0].x + p1 * v4[1].x + p2 * v4[2].x + p3 * v4[3].x;
                    acc[g].y = acc[g].y * corr + p0 * v4[0].y + p1 * v4[1].y + p2 * v4[2].y + p3 * v4[3].y;
                    acc[g].z = acc[g].z * corr + p0 * v4[0].z + p1 * v4[1].z + p2 * v4[2].z + p3 * v4[3].z;
                    acc[g].w = acc[g].w * corr + p0 * v4[0].w + p1 * v4[1].w + p2 * v4[2].w + p3 * v4[3].w;
                    m[g] = mn;
                }
            }
        }

        // Combine the 8 groups via LDS.
#pragma unroll
        for (int g = 0; g < G_; ++g) {
            if (l32 == 0) { lm[gid][g] = m[g]; ll[gid][g] = l[g]; }
            *(float4*)&lacc[gid][g][l32 * 4] = acc[g];
        }
        __syncthreads();

        // 512 (g,d) elements over 256 threads: 2 each. Group 0 is always
        // non-empty (t0 < len); empty groups carry (MINIT_,0,0) -> weight 0.
        float* pbase = ws + (((size_t)(s * KVH_ + kvh) * MAXP_ + part) * G_) * 130;
#pragma unroll
        for (int i = 0; i < 2; ++i) {
            const int idx = tid + 256 * i;
            const int g = idx >> 7;
            const int d = idx & 127;
            float M = lm[0][g];
#pragma unroll
            for (int r = 1; r < 8; ++r) M = fmaxf(M, lm[r][g]);
            float L = 0.f, val = 0.f;
#pragma unroll
            for (int r = 0; r < 8; ++r) {
                const float w = __expf(lm[r][g] - M);
                L   += w * ll[r][g];
                val += w * lacc[r][g][d];
            }
            float* pb = pbase + (size_t)g * 130;
            if (d == 0) { pb[0] = M; pb[1] = L; }
            pb[2 + d] = val;
        }
        // loop top's double-barrier fences lacc reuse for the next item
    }
}

// Combine kernel: one WG (128 threads) per (seq, head); reduce over partitions.
__global__ __launch_bounds__(128)
void pa_combine(const float* __restrict__ ws,
                const int* __restrict__ cl,
                float* __restrict__ out)
{
    const int h = blockIdx.x;   // 0..31
    const int s = blockIdx.y;   // 0..63
    const int kvh = h >> 2;
    const int g   = h & 3;
    const int d   = threadIdx.x;

    const int len = cl[s];
    const int np  = (len + PART_ - 1) / PART_;

    const float* base = ws + ((size_t)(s * KVH_ + kvh) * MAXP_) * (G_ * 130) + (size_t)g * 130;

    float M = MINIT_;
    for (int p = 0; p < np; ++p) M = fmaxf(M, base[(size_t)p * (G_ * 130)]);

    float L = 0.f, val = 0.f;
    for (int p = 0; p < np; ++p) {
        const float* pb = base + (size_t)p * (G_ * 130);
        const float w = __expf(pb[0] - M);
        L   += w * pb[1];
        val += w * pb[2 + d];
    }
    out[((size_t)s * H_ + h) * D_ + d] = val / L;
}

extern "C" void kernel_launch(void* const* d_in, const int* in_sizes, int n_in,
                              void* d_out, int out_size, void* d_ws, size_t ws_size,
                              hipStream_t stream)
{
    const float* q  = (const float*)d_in[0];
    const float* kc = (const float*)d_in[1];
    const float* vc = (const float*)d_in[2];
    const int*   bt = (const int*)d_in[3];
    const int*   cl = (const int*)d_in[4];
    float* out = (float*)d_out;
    float* ws  = (float*)d_ws;

    // ws layout: [S_][KVH_][MAXP_][G_][130] floats = 17.04 MB partials
    // (R2 ran this size successfully), then a 4-byte work counter.
    const size_t partial_floats = (size_t)S_ * KVH_ * MAXP_ * G_ * 130;
    int* counter = (int*)(ws + partial_floats);

    hipMemsetAsync(counter, 0, sizeof(int), stream);

    pa_partial<<<NWG_, 256, 0, stream>>>(q, kc, vc, bt, cl, ws, counter);

    dim3 grid2(H_, S_);
    pa_combine<<<grid2, 128, 0, stream>>>(ws, cl, out);
}